// Round 7
// baseline (208.849 us; speedup 1.0000x reference)
//
#include <hip/hip_runtime.h>
#include <hip/hip_bf16.h>
#include <stdint.h>

#define B_ 4
#define T_ 2048
#define C_ 1024
#define H_ 16
#define DH_ 64
#define M_ (B_*T_)      // 8192
#define NQKV_ (3*C_)    // 3072
#define K_ C_           // 1024

typedef __attribute__((ext_vector_type(8))) short short8;
typedef __attribute__((ext_vector_type(4))) float f32x4;
typedef __attribute__((ext_vector_type(4))) unsigned short us4;

union BFC { __hip_bfloat16 h; unsigned short u; };
__device__ inline unsigned short f2b(float f){ BFC c; c.h = __float2bfloat16(f); return c.u; }

__device__ inline void gload_lds16(const void* g, void* l){
  __builtin_amdgcn_global_load_lds(
    (const __attribute__((address_space(1))) void*)(uintptr_t)g,
    (__attribute__((address_space(3))) void*)(uintptr_t)l,
    16, 0, 0);
}

// ---------------- fp32 -> bf16 convert ----------------
__global__ void cvt_f32_bf16(const float* __restrict__ src,
                             __hip_bfloat16* __restrict__ dst, int n4)
{
  int i = blockIdx.x * blockDim.x + threadIdx.x;
  int stride = gridDim.x * blockDim.x;
  for (; i < n4; i += stride) {
    float4 v = reinterpret_cast<const float4*>(src)[i];
    us4 o;
    o.x = f2b(v.x); o.y = f2b(v.y); o.z = f2b(v.z); o.w = f2b(v.w);
    reinterpret_cast<us4*>(dst)[i] = o;
  }
}

// ---------------- GEMM: Y[M,N] = A[M,K] * B[N,K]^T + bias ----------------
// 128x128 tile, BK=32, 4 waves. 2-PHASE double-buffered (T3-minimum):
// STAGE(t+1) issued before consuming tile t; single barrier per K-step
// (syncthreads drains both the prefetch vmcnt and the ds_reads).
// 1D grid + bijective XCD swizzle (nwg % 8 == 0 for both call sites).
__global__ __launch_bounds__(256) void gemm_bt(
    const __hip_bfloat16* __restrict__ A,
    const __hip_bfloat16* __restrict__ Bw,
    const float* __restrict__ bias,
    int mode, int nbx,
    __hip_bfloat16* __restrict__ qdst,
    __hip_bfloat16* __restrict__ kdst,
    __hip_bfloat16* __restrict__ vdst,
    float* __restrict__ fdst)
{
  __shared__ char a_lds[2][8192];
  __shared__ char b_lds[2][8192];

  const int tid = threadIdx.x;
  const int lane = tid & 63;
  const int w = tid >> 6;
  const int l15 = lane & 15;
  const int lhi = lane >> 4;
  const int wm = w >> 1, wn = w & 1;

  // XCD swizzle: chunk of nwg/8 consecutive logical blocks per XCD
  const int nwg = gridDim.x;
  const int q8 = nwg >> 3;
  const int lb = (blockIdx.x & 7) * q8 + (blockIdx.x >> 3);
  const int bx = lb % nbx, by = lb / nbx;
  const int row0 = by * 128;
  const int col0 = bx * 128;

  int srow[2], scol[2];
#pragma unroll
  for (int j = 0; j < 2; ++j) {
    int L = w * 2048 + j * 1024 + lane * 16;
    int r = L >> 6;
    int cb = (L & 63) ^ (((r >> 1) & 3) << 4);
    srow[j] = r;
    scol[j] = cb >> 1;
  }

  const f32x4 zf = {0.f, 0.f, 0.f, 0.f};
  f32x4 acc[4][4];
#pragma unroll
  for (int m = 0; m < 4; ++m)
#pragma unroll
    for (int n = 0; n < 4; ++n) acc[m][n] = zf;

  const short* Ag = (const short*)A;
  const short* Bg = (const short*)Bw;

#define STAGE(kt, buf)                                                          \
  do {                                                                          \
    gload_lds16(Ag + (size_t)(row0 + srow[0]) * K_ + (kt) + scol[0],            \
                &a_lds[buf][w * 2048]);                                         \
    gload_lds16(Ag + (size_t)(row0 + srow[1]) * K_ + (kt) + scol[1],            \
                &a_lds[buf][w * 2048 + 1024]);                                  \
    gload_lds16(Bg + (size_t)(col0 + srow[0]) * K_ + (kt) + scol[0],            \
                &b_lds[buf][w * 2048]);                                         \
    gload_lds16(Bg + (size_t)(col0 + srow[1]) * K_ + (kt) + scol[1],            \
                &b_lds[buf][w * 2048 + 1024]);                                  \
  } while (0)

  STAGE(0, 0);
  __syncthreads();

  const int NKT = K_ / 32;
  for (int ki = 0; ki < NKT; ++ki) {
    const int cur = ki & 1;
    if (ki + 1 < NKT) STAGE((ki + 1) * 32, cur ^ 1);  // prefetch next tile

    short8 af[4], bfr[4];
#pragma unroll
    for (int m = 0; m < 4; ++m) {
      int r = wm * 64 + m * 16 + l15;
      af[m] = *(const short8*)(&a_lds[cur][r * 64 +
                   ((lhi * 16) ^ (((r >> 1) & 3) << 4))]);
    }
#pragma unroll
    for (int n = 0; n < 4; ++n) {
      int r = wn * 64 + n * 16 + l15;
      bfr[n] = *(const short8*)(&b_lds[cur][r * 64 +
                   ((lhi * 16) ^ (((r >> 1) & 3) << 4))]);
    }
#pragma unroll
    for (int m = 0; m < 4; ++m)
#pragma unroll
      for (int n = 0; n < 4; ++n)
        acc[m][n] = __builtin_amdgcn_mfma_f32_16x16x32_bf16(af[m], bfr[n], acc[m][n], 0, 0, 0);

    __syncthreads();  // releases buf[cur] for next prefetch + publishes buf[cur^1]
  }
#undef STAGE

  if (mode == 0) {
#pragma unroll
    for (int m = 0; m < 4; ++m) {
#pragma unroll
      for (int r = 0; r < 4; ++r) {
        int grow = row0 + wm * 64 + m * 16 + lhi * 4 + r;
        int b = grow >> 11, tt = grow & 2047;
#pragma unroll
        for (int n = 0; n < 4; ++n) {
          int gcol = col0 + wn * 64 + n * 16 + l15;
          float v = acc[m][n][r] + bias[gcol];
          int sel = gcol >> 10;
          int c1 = gcol & 1023;
          int hh = c1 >> 6, dh = c1 & 63;
          __hip_bfloat16 bv = __float2bfloat16(v);
          if (sel == 0)
            qdst[(((size_t)(b * H_ + hh)) * T_ + tt) * DH_ + dh] = bv;
          else if (sel == 1)
            kdst[(((size_t)(b * H_ + hh)) * T_ + tt) * DH_ + dh] = bv;
          else  // V stored transposed: [B,H,DH,T]
            vdst[(((size_t)(b * H_ + hh)) * DH_ + dh) * T_ + tt] = bv;
        }
      }
    }
  } else {
#pragma unroll
    for (int m = 0; m < 4; ++m) {
#pragma unroll
      for (int r = 0; r < 4; ++r) {
        int grow = row0 + wm * 64 + m * 16 + lhi * 4 + r;
#pragma unroll
        for (int n = 0; n < 4; ++n) {
          int gcol = col0 + wn * 64 + n * 16 + l15;
          fdst[(size_t)grow * C_ + gcol] = acc[m][n][r] + bias[gcol];
        }
      }
    }
  }
}

// ---------------- causal flash attention, LDS-staged K/V (8-wave reuse) -------
// Stages each K/V tile ONCE per 256-row q-block (8 waves share it).
// grid = 512: bh = blk&63 (XCD-local); qb paired heavy+light across grid halves.
// Staging: 1 global_load_lds(16B)/thread/buffer, both-sides XOR swizzle.
// Double-buffered: stage(t+1) issued before compute(t); 1 barrier/iter.
// Waves past their causal diagonal skip compute but keep barriers.
__global__ __launch_bounds__(512, 2) void attn_kernel(
    const __hip_bfloat16* __restrict__ qg,
    const __hip_bfloat16* __restrict__ kg,
    const __hip_bfloat16* __restrict__ vtg,
    __hip_bfloat16* __restrict__ og)
{
  __shared__ char k_lds[2][8192];    // [buf][kv 64][dh 64] bf16, swz ((row&7)<<4)
  __shared__ char v_lds[2][8192];    // [buf][dh 64][kv 64] bf16 (V^T), same swz
  __shared__ char p_lds[8][4096];    // per-wave [32][64] bf16, swz ((row&7)<<4)

  const int tid = threadIdx.x;
  const int lane = tid & 63;
  const int w = tid >> 6;            // 0..7
  const int l15 = lane & 15;
  const int lhi = lane >> 4;
  const int blk = blockIdx.x;
  const int bh = blk & 63;           // same-head blocks share XCD (blk%8 == bh%8)
  const int g = blk >> 6;            // 0..7
  const int qb = (g < 4) ? g : 11 - g;  // halves pair qb={0..3} with {7..4}
  const int qr0 = qb * 256 + w * 32;
  const int nt = 4 * (qb + 1);
  const int tmask = qr0 >> 6;        // last tile this wave must compute

  const char* kpb = (const char*)(kg + (size_t)bh * T_ * DH_);
  const char* vtpb = (const char*)(vtg + (size_t)bh * DH_ * T_);
  const short* qp = (const short*)(qg + (size_t)bh * T_ * DH_);
  char* pwl = p_lds[w];

  const int srow = tid >> 3;
  const int scb = ((tid & 7) << 4) ^ ((srow & 7) << 4);
  const int sdst = tid * 16;

  short8 qf[2][2];
#pragma unroll
  for (int m = 0; m < 2; ++m)
#pragma unroll
    for (int kf = 0; kf < 2; ++kf)
      qf[m][kf] = *(const short8*)(qp + (size_t)(qr0 + m * 16 + l15) * DH_ +
                                   kf * 32 + lhi * 8);

  const f32x4 zf = {0.f, 0.f, 0.f, 0.f};
  f32x4 o[2][4];
  float lsum[2][4];
#pragma unroll
  for (int m = 0; m < 2; ++m) {
#pragma unroll
    for (int n = 0; n < 4; ++n) o[m][n] = zf;
#pragma unroll
    for (int r = 0; r < 4; ++r) lsum[m][r] = 0.f;
  }

  gload_lds16(kpb + (size_t)srow * 128 + scb, &k_lds[0][sdst]);
  gload_lds16(vtpb + (size_t)srow * 4096 + scb, &v_lds[0][sdst]);
  __syncthreads();

  for (int t = 0; t < nt; ++t) {
    const int cur = t & 1;
    if (t + 1 < nt) {
      const int kv1 = (t + 1) * 64;
      gload_lds16(kpb + (size_t)(kv1 + srow) * 128 + scb, &k_lds[cur ^ 1][sdst]);
      gload_lds16(vtpb + (size_t)srow * 4096 + kv1 * 2 + scb, &v_lds[cur ^ 1][sdst]);
    }

    if (t <= tmask) {
      const int kv0 = t * 64;

      short8 kfr[2][4];
#pragma unroll
      for (int kf = 0; kf < 2; ++kf)
#pragma unroll
        for (int n = 0; n < 4; ++n) {
          int kr = n * 16 + l15;
          kfr[kf][n] = *(const short8*)(&k_lds[cur][kr * 128 +
                           ((kf * 64 + lhi * 16) ^ ((kr & 7) << 4))]);
        }

      f32x4 s[2][4];
#pragma unroll
      for (int m = 0; m < 2; ++m)
#pragma unroll
        for (int n = 0; n < 4; ++n) s[m][n] = zf;
#pragma unroll
      for (int kf = 0; kf < 2; ++kf)
#pragma unroll
        for (int n = 0; n < 4; ++n)
#pragma unroll
          for (int m = 0; m < 2; ++m)
            s[m][n] = __builtin_amdgcn_mfma_f32_16x16x32_bf16(qf[m][kf], kfr[kf][n],
                                                              s[m][n], 0, 0, 0);

      short8 vfr[2][4];
#pragma unroll
      for (int kf = 0; kf < 2; ++kf)
#pragma unroll
        for (int n = 0; n < 4; ++n) {
          int vr = n * 16 + l15;
          vfr[kf][n] = *(const short8*)(&v_lds[cur][vr * 128 +
                           ((kf * 64 + lhi * 16) ^ ((vr & 7) << 4))]);
        }

      if (t == tmask) {
#pragma unroll
        for (int m = 0; m < 2; ++m)
#pragma unroll
          for (int n = 0; n < 4; ++n)
#pragma unroll
            for (int r = 0; r < 4; ++r) {
              int kvA = kv0 + n * 16 + l15;
              int qA = qr0 + m * 16 + lhi * 4 + r;
              if (kvA > qA) s[m][n][r] = -1e30f;
            }
      }

#pragma unroll
      for (int m = 0; m < 2; ++m)
#pragma unroll
        for (int n = 0; n < 4; ++n)
#pragma unroll
          for (int r = 0; r < 4; ++r) {
            float pe = __expf(s[m][n][r] * 0.125f);
            s[m][n][r] = pe;
            lsum[m][r] += pe;
          }

#pragma unroll
      for (int m = 0; m < 2; ++m)
#pragma unroll
        for (int n = 0; n < 4; ++n)
#pragma unroll
          for (int r = 0; r < 4; ++r) {
            int row = m * 16 + lhi * 4 + r;
            *(unsigned short*)(pwl + row * 128 +
                               (((n * 16 + l15) * 2) ^ ((row & 7) << 4))) =
                f2b(s[m][n][r]);
          }
      short8 pa[2][2];
#pragma unroll
      for (int m = 0; m < 2; ++m)
#pragma unroll
        for (int kf = 0; kf < 2; ++kf) {
          int row = m * 16 + l15;
          pa[m][kf] = *(const short8*)(pwl + row * 128 +
                                       ((kf * 64 + lhi * 16) ^ ((row & 7) << 4)));
        }

#pragma unroll
      for (int kf = 0; kf < 2; ++kf)
#pragma unroll
        for (int n = 0; n < 4; ++n)
#pragma unroll
          for (int m = 0; m < 2; ++m)
            o[m][n] = __builtin_amdgcn_mfma_f32_16x16x32_bf16(pa[m][kf], vfr[kf][n],
                                                              o[m][n], 0, 0, 0);
    }

    __syncthreads();
  }

#pragma unroll
  for (int m = 0; m < 2; ++m)
#pragma unroll
    for (int r = 0; r < 4; ++r)
#pragma unroll
      for (int d = 1; d < 16; d <<= 1)
        lsum[m][r] += __shfl_xor(lsum[m][r], d, 64);

  const int b = bh >> 4, hd = bh & 15;
#pragma unroll
  for (int m = 0; m < 2; ++m)
#pragma unroll
    for (int r = 0; r < 4; ++r) {
      float inv = 1.f / lsum[m][r];
      int qrow = qr0 + m * 16 + lhi * 4 + r;
      __hip_bfloat16* orow = og + ((size_t)(b * T_ + qrow)) * C_ + hd * DH_;
#pragma unroll
      for (int n = 0; n < 4; ++n)
        orow[n * 16 + l15] = __float2bfloat16(o[m][n][r] * inv);
    }
}

// ---------------- launch ----------------
extern "C" void kernel_launch(void* const* d_in, const int* in_sizes, int n_in,
                              void* d_out, int out_size, void* d_ws, size_t ws_size,
                              hipStream_t stream) {
  const float* x      = (const float*)d_in[0];
  const float* qkv_w  = (const float*)d_in[1];
  const float* qkv_b  = (const float*)d_in[2];
  const float* proj_w = (const float*)d_in[3];
  const float* proj_b = (const float*)d_in[4];
  float* out = (float*)d_out;

  char* ws = (char*)d_ws;
  __hip_bfloat16* xb    = (__hip_bfloat16*)(ws);                 // 16 MB
  __hip_bfloat16* wqkv  = (__hip_bfloat16*)(ws + 16777216);      // 6 MB
  __hip_bfloat16* wproj = (__hip_bfloat16*)(ws + 23068672);      // 2 MB
  __hip_bfloat16* qb    = (__hip_bfloat16*)(ws + 25165824);      // 16 MB
  __hip_bfloat16* kb    = (__hip_bfloat16*)(ws + 41943040);      // 16 MB
  __hip_bfloat16* vtb   = (__hip_bfloat16*)(ws + 58720256);      // 16 MB (V^T)
  __hip_bfloat16* att   = (__hip_bfloat16*)(ws + 75497472);      // 16 MB

  cvt_f32_bf16<<<2048, 256, 0, stream>>>(x, xb, M_ * K_ / 4);
  cvt_f32_bf16<<<1024, 256, 0, stream>>>(qkv_w, wqkv, NQKV_ * K_ / 4);
  cvt_f32_bf16<<<512, 256, 0, stream>>>(proj_w, wproj, C_ * K_ / 4);

  // QKV: nwg = 24*64 = 1536 (divisible by 8)
  gemm_bt<<<dim3((NQKV_/128) * (M_/128)), 256, 0, stream>>>(
      xb, wqkv, qkv_b, 0, NQKV_/128, qb, kb, vtb, nullptr);

  attn_kernel<<<dim3(512), 512, 0, stream>>>(qb, kb, vtb, att);

  // proj: nwg = 8*64 = 512 (divisible by 8)
  gemm_bt<<<dim3((C_/128) * (M_/128)), 256, 0, stream>>>(
      att, wproj, proj_b, 1, C_/128, nullptr, nullptr, nullptr, out);
}

// Round 8
// 200.917 us; speedup vs baseline: 1.0395x; 1.0395x over previous
//
#include <hip/hip_runtime.h>
#include <hip/hip_bf16.h>
#include <stdint.h>

#define B_ 4
#define T_ 2048
#define C_ 1024
#define H_ 16
#define DH_ 64
#define M_ (B_*T_)      // 8192
#define NQKV_ (3*C_)    // 3072
#define K_ C_           // 1024

typedef __attribute__((ext_vector_type(8))) short short8;
typedef __attribute__((ext_vector_type(4))) float f32x4;
typedef __attribute__((ext_vector_type(4))) unsigned short us4;

union BFC { __hip_bfloat16 h; unsigned short u; };
__device__ inline unsigned short f2b(float f){ BFC c; c.h = __float2bfloat16(f); return c.u; }

__device__ inline void gload_lds16(const void* g, void* l){
  __builtin_amdgcn_global_load_lds(
    (const __attribute__((address_space(1))) void*)(uintptr_t)g,
    (__attribute__((address_space(3))) void*)(uintptr_t)l,
    16, 0, 0);
}

// ---------------- fp32 -> bf16 convert ----------------
__global__ void cvt_f32_bf16(const float* __restrict__ src,
                             __hip_bfloat16* __restrict__ dst, int n4)
{
  int i = blockIdx.x * blockDim.x + threadIdx.x;
  int stride = gridDim.x * blockDim.x;
  for (; i < n4; i += stride) {
    float4 v = reinterpret_cast<const float4*>(src)[i];
    us4 o;
    o.x = f2b(v.x); o.y = f2b(v.y); o.z = f2b(v.z); o.w = f2b(v.w);
    reinterpret_cast<us4*>(dst)[i] = o;
  }
}

// ---------------- GEMM: Y[M,N] = A[M,K] * B[N,K]^T + bias ----------------
// 256x256 tile, BK=64, 8 waves (2x4), each wave 128x64 (8x4 of 16x16x32 MFMA).
// R7 showed the 128^2 tile is staging-BW-bound (786 MB @ ~6.4 TB/s = the whole
// 124us); 256^2 halves staged traffic. 2-phase double-buffer, LDS 128 KB.
// Rows are 128 B -> XOR swizzle ((r&7)<<4) both sides (write-src + read).
// 1D grid + bijective XCD swizzle (nwg % 8 == 0 at both call sites).
__global__ __launch_bounds__(512) void gemm_bt(
    const __hip_bfloat16* __restrict__ A,
    const __hip_bfloat16* __restrict__ Bw,
    const float* __restrict__ bias,
    int mode, int nbx,
    __hip_bfloat16* __restrict__ qdst,
    __hip_bfloat16* __restrict__ kdst,
    __hip_bfloat16* __restrict__ vdst,
    float* __restrict__ fdst)
{
  __shared__ char a_lds[2][32768];   // [buf][256 rows][64 bf16]
  __shared__ char b_lds[2][32768];

  const int tid = threadIdx.x;
  const int lane = tid & 63;
  const int w = tid >> 6;            // 0..7
  const int l15 = lane & 15;
  const int lhi = lane >> 4;
  const int wm = w >> 2, wn = w & 3; // wave grid 2 x 4

  const int nwg = gridDim.x;
  const int q8 = nwg >> 3;
  const int lb = (blockIdx.x & 7) * q8 + (blockIdx.x >> 3);
  const int bx = lb % nbx, by = lb / nbx;
  const int row0 = by * 256;
  const int col0 = bx * 256;

  // staging decode: issue i covers LDS bytes [i*8192 + tid*16, +16)
  // lds[r*128+c] = G[r][c ^ ((r&7)<<4)]  (linear dest, inverse-swizzled src)
  int srow[4], scol[4];
#pragma unroll
  for (int i = 0; i < 4; ++i) {
    int L = i * 8192 + tid * 16;
    int r = L >> 7;
    int cb = (L & 127) ^ ((r & 7) << 4);
    srow[i] = r;
    scol[i] = cb >> 1;
  }

  const f32x4 zf = {0.f, 0.f, 0.f, 0.f};
  f32x4 acc[8][4];
#pragma unroll
  for (int m = 0; m < 8; ++m)
#pragma unroll
    for (int n = 0; n < 4; ++n) acc[m][n] = zf;

  const short* Ag = (const short*)A;
  const short* Bg = (const short*)Bw;

#define STAGE(kt, buf)                                                          \
  do {                                                                          \
    _Pragma("unroll")                                                           \
    for (int i = 0; i < 4; ++i) {                                               \
      gload_lds16(Ag + (size_t)(row0 + srow[i]) * K_ + (kt) + scol[i],          \
                  &a_lds[buf][i * 8192 + tid * 16]);                            \
      gload_lds16(Bg + (size_t)(col0 + srow[i]) * K_ + (kt) + scol[i],          \
                  &b_lds[buf][i * 8192 + tid * 16]);                            \
    }                                                                           \
  } while (0)

  STAGE(0, 0);
  __syncthreads();

  const int NKT = K_ / 64;   // 16
  for (int ki = 0; ki < NKT; ++ki) {
    const int cur = ki & 1;
    if (ki + 1 < NKT) STAGE((ki + 1) * 64, cur ^ 1);  // prefetch next K-tile

#pragma unroll
    for (int kf = 0; kf < 2; ++kf) {
      short8 af[8], bfr[4];
#pragma unroll
      for (int m = 0; m < 8; ++m) {
        int r = wm * 128 + m * 16 + l15;
        af[m] = *(const short8*)(&a_lds[cur][r * 128 +
                     ((kf * 64 + lhi * 16) ^ ((r & 7) << 4))]);
      }
#pragma unroll
      for (int n = 0; n < 4; ++n) {
        int r = wn * 64 + n * 16 + l15;
        bfr[n] = *(const short8*)(&b_lds[cur][r * 128 +
                     ((kf * 64 + lhi * 16) ^ ((r & 7) << 4))]);
      }
#pragma unroll
      for (int m = 0; m < 8; ++m)
#pragma unroll
        for (int n = 0; n < 4; ++n)
          acc[m][n] = __builtin_amdgcn_mfma_f32_16x16x32_bf16(af[m], bfr[n],
                                                              acc[m][n], 0, 0, 0);
    }

    __syncthreads();  // releases buf[cur]; publishes buf[cur^1]
  }
#undef STAGE

  if (mode == 0) {
#pragma unroll
    for (int m = 0; m < 8; ++m) {
#pragma unroll
      for (int r = 0; r < 4; ++r) {
        int grow = row0 + wm * 128 + m * 16 + lhi * 4 + r;
        int b = grow >> 11, tt = grow & 2047;
#pragma unroll
        for (int n = 0; n < 4; ++n) {
          int gcol = col0 + wn * 64 + n * 16 + l15;
          float v = acc[m][n][r] + bias[gcol];
          int sel = gcol >> 10;
          int c1 = gcol & 1023;
          int hh = c1 >> 6, dh = c1 & 63;
          __hip_bfloat16 bv = __float2bfloat16(v);
          if (sel == 0)
            qdst[(((size_t)(b * H_ + hh)) * T_ + tt) * DH_ + dh] = bv;
          else if (sel == 1)
            kdst[(((size_t)(b * H_ + hh)) * T_ + tt) * DH_ + dh] = bv;
          else  // V stored transposed: [B,H,DH,T]
            vdst[(((size_t)(b * H_ + hh)) * DH_ + dh) * T_ + tt] = bv;
        }
      }
    }
  } else {
#pragma unroll
    for (int m = 0; m < 8; ++m) {
#pragma unroll
      for (int r = 0; r < 4; ++r) {
        int grow = row0 + wm * 128 + m * 16 + lhi * 4 + r;
#pragma unroll
        for (int n = 0; n < 4; ++n) {
          int gcol = col0 + wn * 64 + n * 16 + l15;
          fdst[(size_t)grow * C_ + gcol] = acc[m][n][r] + bias[gcol];
        }
      }
    }
  }
}

// ---------------- causal flash attention, LDS-staged K/V (8-wave reuse) -------
// Stages each K/V tile ONCE per 256-row q-block (8 waves share it).
// grid = 512: bh = blk&63 (XCD-local); qb paired heavy+light across grid halves.
// Staging: 1 global_load_lds(16B)/thread/buffer, both-sides XOR swizzle.
// Double-buffered: stage(t+1) issued before compute(t); 1 barrier/iter.
// Waves past their causal diagonal skip compute but keep barriers.
__global__ __launch_bounds__(512, 2) void attn_kernel(
    const __hip_bfloat16* __restrict__ qg,
    const __hip_bfloat16* __restrict__ kg,
    const __hip_bfloat16* __restrict__ vtg,
    __hip_bfloat16* __restrict__ og)
{
  __shared__ char k_lds[2][8192];    // [buf][kv 64][dh 64] bf16, swz ((row&7)<<4)
  __shared__ char v_lds[2][8192];    // [buf][dh 64][kv 64] bf16 (V^T), same swz
  __shared__ char p_lds[8][4096];    // per-wave [32][64] bf16, swz ((row&7)<<4)

  const int tid = threadIdx.x;
  const int lane = tid & 63;
  const int w = tid >> 6;            // 0..7
  const int l15 = lane & 15;
  const int lhi = lane >> 4;
  const int blk = blockIdx.x;
  const int bh = blk & 63;           // same-head blocks share XCD (blk%8 == bh%8)
  const int g = blk >> 6;            // 0..7
  const int qb = (g < 4) ? g : 11 - g;  // halves pair qb={0..3} with {7..4}
  const int qr0 = qb * 256 + w * 32;
  const int nt = 4 * (qb + 1);
  const int tmask = qr0 >> 6;        // last tile this wave must compute

  const char* kpb = (const char*)(kg + (size_t)bh * T_ * DH_);
  const char* vtpb = (const char*)(vtg + (size_t)bh * DH_ * T_);
  const short* qp = (const short*)(qg + (size_t)bh * T_ * DH_);
  char* pwl = p_lds[w];

  const int srow = tid >> 3;
  const int scb = ((tid & 7) << 4) ^ ((srow & 7) << 4);
  const int sdst = tid * 16;

  short8 qf[2][2];
#pragma unroll
  for (int m = 0; m < 2; ++m)
#pragma unroll
    for (int kf = 0; kf < 2; ++kf)
      qf[m][kf] = *(const short8*)(qp + (size_t)(qr0 + m * 16 + l15) * DH_ +
                                   kf * 32 + lhi * 8);

  const f32x4 zf = {0.f, 0.f, 0.f, 0.f};
  f32x4 o[2][4];
  float lsum[2][4];
#pragma unroll
  for (int m = 0; m < 2; ++m) {
#pragma unroll
    for (int n = 0; n < 4; ++n) o[m][n] = zf;
#pragma unroll
    for (int r = 0; r < 4; ++r) lsum[m][r] = 0.f;
  }

  gload_lds16(kpb + (size_t)srow * 128 + scb, &k_lds[0][sdst]);
  gload_lds16(vtpb + (size_t)srow * 4096 + scb, &v_lds[0][sdst]);
  __syncthreads();

  for (int t = 0; t < nt; ++t) {
    const int cur = t & 1;
    if (t + 1 < nt) {
      const int kv1 = (t + 1) * 64;
      gload_lds16(kpb + (size_t)(kv1 + srow) * 128 + scb, &k_lds[cur ^ 1][sdst]);
      gload_lds16(vtpb + (size_t)srow * 4096 + kv1 * 2 + scb, &v_lds[cur ^ 1][sdst]);
    }

    if (t <= tmask) {
      const int kv0 = t * 64;

      short8 kfr[2][4];
#pragma unroll
      for (int kf = 0; kf < 2; ++kf)
#pragma unroll
        for (int n = 0; n < 4; ++n) {
          int kr = n * 16 + l15;
          kfr[kf][n] = *(const short8*)(&k_lds[cur][kr * 128 +
                           ((kf * 64 + lhi * 16) ^ ((kr & 7) << 4))]);
        }

      f32x4 s[2][4];
#pragma unroll
      for (int m = 0; m < 2; ++m)
#pragma unroll
        for (int n = 0; n < 4; ++n) s[m][n] = zf;
#pragma unroll
      for (int kf = 0; kf < 2; ++kf)
#pragma unroll
        for (int n = 0; n < 4; ++n)
#pragma unroll
          for (int m = 0; m < 2; ++m)
            s[m][n] = __builtin_amdgcn_mfma_f32_16x16x32_bf16(qf[m][kf], kfr[kf][n],
                                                              s[m][n], 0, 0, 0);

      short8 vfr[2][4];
#pragma unroll
      for (int kf = 0; kf < 2; ++kf)
#pragma unroll
        for (int n = 0; n < 4; ++n) {
          int vr = n * 16 + l15;
          vfr[kf][n] = *(const short8*)(&v_lds[cur][vr * 128 +
                           ((kf * 64 + lhi * 16) ^ ((vr & 7) << 4))]);
        }

      if (t == tmask) {
#pragma unroll
        for (int m = 0; m < 2; ++m)
#pragma unroll
          for (int n = 0; n < 4; ++n)
#pragma unroll
            for (int r = 0; r < 4; ++r) {
              int kvA = kv0 + n * 16 + l15;
              int qA = qr0 + m * 16 + lhi * 4 + r;
              if (kvA > qA) s[m][n][r] = -1e30f;
            }
      }

#pragma unroll
      for (int m = 0; m < 2; ++m)
#pragma unroll
        for (int n = 0; n < 4; ++n)
#pragma unroll
          for (int r = 0; r < 4; ++r) {
            float pe = __expf(s[m][n][r] * 0.125f);
            s[m][n][r] = pe;
            lsum[m][r] += pe;
          }

#pragma unroll
      for (int m = 0; m < 2; ++m)
#pragma unroll
        for (int n = 0; n < 4; ++n)
#pragma unroll
          for (int r = 0; r < 4; ++r) {
            int row = m * 16 + lhi * 4 + r;
            *(unsigned short*)(pwl + row * 128 +
                               (((n * 16 + l15) * 2) ^ ((row & 7) << 4))) =
                f2b(s[m][n][r]);
          }
      short8 pa[2][2];
#pragma unroll
      for (int m = 0; m < 2; ++m)
#pragma unroll
        for (int kf = 0; kf < 2; ++kf) {
          int row = m * 16 + l15;
          pa[m][kf] = *(const short8*)(pwl + row * 128 +
                                       ((kf * 64 + lhi * 16) ^ ((row & 7) << 4)));
        }

#pragma unroll
      for (int kf = 0; kf < 2; ++kf)
#pragma unroll
        for (int n = 0; n < 4; ++n)
#pragma unroll
          for (int m = 0; m < 2; ++m)
            o[m][n] = __builtin_amdgcn_mfma_f32_16x16x32_bf16(pa[m][kf], vfr[kf][n],
                                                              o[m][n], 0, 0, 0);
    }

    __syncthreads();
  }

#pragma unroll
  for (int m = 0; m < 2; ++m)
#pragma unroll
    for (int r = 0; r < 4; ++r)
#pragma unroll
      for (int d = 1; d < 16; d <<= 1)
        lsum[m][r] += __shfl_xor(lsum[m][r], d, 64);

  const int b = bh >> 4, hd = bh & 15;
#pragma unroll
  for (int m = 0; m < 2; ++m)
#pragma unroll
    for (int r = 0; r < 4; ++r) {
      float inv = 1.f / lsum[m][r];
      int qrow = qr0 + m * 16 + lhi * 4 + r;
      __hip_bfloat16* orow = og + ((size_t)(b * T_ + qrow)) * C_ + hd * DH_;
#pragma unroll
      for (int n = 0; n < 4; ++n)
        orow[n * 16 + l15] = __float2bfloat16(o[m][n][r] * inv);
    }
}

// ---------------- launch ----------------
extern "C" void kernel_launch(void* const* d_in, const int* in_sizes, int n_in,
                              void* d_out, int out_size, void* d_ws, size_t ws_size,
                              hipStream_t stream) {
  const float* x      = (const float*)d_in[0];
  const float* qkv_w  = (const float*)d_in[1];
  const float* qkv_b  = (const float*)d_in[2];
  const float* proj_w = (const float*)d_in[3];
  const float* proj_b = (const float*)d_in[4];
  float* out = (float*)d_out;

  char* ws = (char*)d_ws;
  __hip_bfloat16* xb    = (__hip_bfloat16*)(ws);                 // 16 MB
  __hip_bfloat16* wqkv  = (__hip_bfloat16*)(ws + 16777216);      // 6 MB
  __hip_bfloat16* wproj = (__hip_bfloat16*)(ws + 23068672);      // 2 MB
  __hip_bfloat16* qb    = (__hip_bfloat16*)(ws + 25165824);      // 16 MB
  __hip_bfloat16* kb    = (__hip_bfloat16*)(ws + 41943040);      // 16 MB
  __hip_bfloat16* vtb   = (__hip_bfloat16*)(ws + 58720256);      // 16 MB (V^T)
  __hip_bfloat16* att   = (__hip_bfloat16*)(ws + 75497472);      // 16 MB

  cvt_f32_bf16<<<2048, 256, 0, stream>>>(x, xb, M_ * K_ / 4);
  cvt_f32_bf16<<<1024, 256, 0, stream>>>(qkv_w, wqkv, NQKV_ * K_ / 4);
  cvt_f32_bf16<<<512, 256, 0, stream>>>(proj_w, wproj, C_ * K_ / 4);

  // QKV: nwg = 12*32 = 384 (divisible by 8)
  gemm_bt<<<dim3((NQKV_/256) * (M_/256)), 512, 0, stream>>>(
      xb, wqkv, qkv_b, 0, NQKV_/256, qb, kb, vtb, nullptr);

  attn_kernel<<<dim3(512), 512, 0, stream>>>(qb, kb, vtb, att);

  // proj: nwg = 4*32 = 128 (divisible by 8)
  gemm_bt<<<dim3((C_/256) * (M_/256)), 512, 0, stream>>>(
      att, wproj, proj_b, 1, C_/256, nullptr, nullptr, nullptr, out);
}